// Round 4
// baseline (979.212 us; speedup 1.0000x reference)
//
#include <hip/hip_runtime.h>
#include <stdint.h>

typedef unsigned short u16;
typedef short bf16x8 __attribute__((ext_vector_type(8)));
typedef float f32x4 __attribute__((ext_vector_type(4)));

__device__ __forceinline__ float b2f(u16 u){
  unsigned int i = ((unsigned int)u) << 16;
  return __builtin_bit_cast(float, i);
}
__device__ __forceinline__ u16 f2b(float f){
  unsigned int i = __builtin_bit_cast(unsigned int, f);
  i += 0x7FFFu + ((i >> 16) & 1u);   // round-nearest-even
  return (u16)(i >> 16);
}

__device__ __forceinline__ void async16(const void* g, void* l){
  __builtin_amdgcn_global_load_lds((__attribute__((address_space(1))) void*)(void*)g,
                                   (__attribute__((address_space(3))) void*)l, 16, 0, 0);
}

// ---------------- dtype probe: flag=1 if external tensors are fp32 ----------------
__global__ void probe_kernel(const u16* __restrict__ qw, int* __restrict__ flag){
  if (threadIdx.x == 0){
    int cnt = 0;
    for (int i = 0; i < 4096; ++i){
      int e = (qw[i] >> 7) & 0xFF;
      cnt += (e >= 140);
    }
    *flag = (cnt > 64) ? 1 : 0;
  }
}

// ---------------- convert external weight -> bf16 (8 elems/thread) ----------------
__global__ __launch_bounds__(256) void cvt_kernel(const void* __restrict__ src,
                                                  u16* __restrict__ dst, int n,
                                                  const int* __restrict__ flagp){
  const int i = (blockIdx.x * 256 + threadIdx.x) * 8;
  if (i >= n) return;
  if (*flagp){
    f32x4 a = *(const f32x4*)((const float*)src + i);
    f32x4 b = *(const f32x4*)((const float*)src + i + 4);
    bf16x8 v;
#pragma unroll
    for (int j = 0; j < 4; ++j){ v[j] = (short)f2b(a[j]); v[4+j] = (short)f2b(b[j]); }
    *(bf16x8*)(dst + i) = v;
  } else {
    *(bf16x8*)(dst + i) = *(const bf16x8*)((const u16*)src + i);
  }
}

// bias -> fp32
__global__ void cvtb_kernel(const void* __restrict__ src, float* __restrict__ dst,
                            int n, const int* __restrict__ flagp){
  int i = blockIdx.x * 256 + threadIdx.x;
  if (i < n) dst[i] = *flagp ? ((const float*)src)[i] : b2f(((const u16*)src)[i]);
}

// ---------------- top-k: rank-by-counting, tie-break lower index ----------------
__global__ __launch_bounds__(576) void topk_kernel(const void* __restrict__ aa,
                                                   int* __restrict__ qrows,
                                                   const int* __restrict__ flagp){
  const int b = blockIdx.x;
  const int isf32 = *flagp;
  __shared__ float vals[576];
  const int i = threadIdx.x;           // 0..575
  const size_t off = (size_t)b*332929 + 1 + i;   // 577*577
  vals[i] = isf32 ? ((const float*)aa)[off] : b2f(((const u16*)aa)[off]);
  __syncthreads();
  const float vi = vals[i];
  int rank = 0;
  for (int j = 0; j < 576; ++j){
    float vj = vals[j];
    rank += (int)((vj > vi) || (vj == vi && j < i));
  }
  if (rank < 57) qrows[b*58 + 1 + rank] = b*577 + i + 1;
  if (i == 0)    qrows[b*58] = b*577;
}

// ---------------- fused A-resident GEMM: [K | Vt | proj-out] ----------------
// Block = 64 rows of x staged once into LDS (padded stride 776 -> 2-way-free b128
// reads, conflict-free staging writes). Then 9 passes x 24 K-iters of a
// BARRIER-FREE inner loop: W fragments loaded global->VGPR (W3 is L2-resident),
// A fragments ds_read_b128, 16 MFMA per wave per iter.
#define ALD 776   // 768 + 8 pad (stride in u16; 1552 B, 16B-aligned, 2-way banks)
__global__ __launch_bounds__(256) void gemm_fused(
    const void* __restrict__ X, const u16* __restrict__ W3,
    u16* __restrict__ Kbuf, u16* __restrict__ Vt, float* __restrict__ Out,
    const float* __restrict__ bias, const int* __restrict__ flagp)
{
  __shared__ __align__(16) u16 Alds[64 * ALD];   // 99,328 B
  const int tid = threadIdx.x;
  const int mBase = blockIdx.x * 64;

  // ---- stage A (64x768) once; coalesced global, conflict-free ds_write ----
  if (*flagp){
    const float* Xf = (const float*)X;
#pragma unroll
    for (int c = 0; c < 24; ++c){
      int id = c*256 + tid;
      int row = id / 96;
      int k16 = id - row*96;
      const float* src = Xf + (size_t)(mBase + row)*768 + k16*8;
      f32x4 a = *(const f32x4*)src;
      f32x4 b = *(const f32x4*)(src + 4);
      bf16x8 v;
#pragma unroll
      for (int j = 0; j < 4; ++j){ v[j] = (short)f2b(a[j]); v[4+j] = (short)f2b(b[j]); }
      *(bf16x8*)&Alds[row*ALD + k16*8] = v;
    }
  } else {
    const u16* Xb = (const u16*)X;
#pragma unroll
    for (int c = 0; c < 24; ++c){
      int id = c*256 + tid;
      int row = id / 96;
      int k16 = id - row*96;
      *(bf16x8*)&Alds[row*ALD + k16*8] = *(const bf16x8*)(Xb + (size_t)(mBase + row)*768 + k16*8);
    }
  }
  __syncthreads();   // the ONLY barrier

  const int w = tid >> 6, l = tid & 63;
  const int lm = l & 15, lk = (l >> 4) * 8;
  const int q4 = (l >> 4) << 2;
  const int wn = w * 64;

  // precompute Vt row decomposition for this wave's 16 m-rows
  int vbb[4][4], vnn[4][4];
#pragma unroll
  for (int i = 0; i < 4; ++i)
#pragma unroll
    for (int r = 0; r < 4; ++r){
      int grow = mBase + i*16 + q4 + r;
      int bb = grow / 577;
      vbb[i][r] = bb;
      vnn[i][r] = grow - bb*577;
    }

  for (int pass = 0; pass < 9; ++pass){
    const int nb = pass*256 + wn;                 // wave's n-base (64 wide)
    const u16* Wp = W3 + (size_t)nb * 768;
    f32x4 acc[4][4] = {};
#pragma unroll 4
    for (int kk = 0; kk < 24; ++kk){
      const int k0 = kk*32;
      bf16x8 af[4], bfr[4];
#pragma unroll
      for (int j = 0; j < 4; ++j) bfr[j] = *(const bf16x8*)&Wp[(size_t)(j*16 + lm)*768 + k0 + lk];
#pragma unroll
      for (int i = 0; i < 4; ++i) af[i]  = *(const bf16x8*)&Alds[(i*16 + lm)*ALD + k0 + lk];
#pragma unroll
      for (int i = 0; i < 4; ++i)
#pragma unroll
        for (int j = 0; j < 4; ++j)
          acc[i][j] = __builtin_amdgcn_mfma_f32_16x16x32_bf16(af[i], bfr[j], acc[i][j], 0, 0, 0);
    }
    // ---- epilogue (wave-uniform section per pass) ----
    if (nb < 768){                       // K-buffer, bf16 row-major
#pragma unroll
      for (int i = 0; i < 4; ++i)
#pragma unroll
        for (int r = 0; r < 4; ++r){
          size_t base = (size_t)(mBase + i*16 + q4 + r) * 768 + nb;
#pragma unroll
          for (int j = 0; j < 4; ++j)
            Kbuf[base + j*16 + lm] = f2b(acc[i][j][r]);
        }
    } else if (nb < 1536){               // Vt[b][h][d][n], stride 608, bf16
      const int nf0 = nb - 768;
#pragma unroll
      for (int i = 0; i < 4; ++i)
#pragma unroll
        for (int r = 0; r < 4; ++r){
          const size_t vb = (size_t)vbb[i][r] * 12;
          const int nn = vnn[i][r];
#pragma unroll
          for (int j = 0; j < 4; ++j){
            int nf = nf0 + j*16 + lm;
            Vt[((vb + (nf >> 6))*64 + (nf & 63))*608 + nn] = f2b(acc[i][j][r]);
          }
        }
    } else {                             // projection output, fp32 + bias
      const int c0 = nb - 1536;
#pragma unroll
      for (int i = 0; i < 4; ++i)
#pragma unroll
        for (int r = 0; r < 4; ++r){
          size_t base = (size_t)(mBase + i*16 + q4 + r) * 768 + c0;
#pragma unroll
          for (int j = 0; j < 4; ++j)
            Out[base + j*16 + lm] = acc[i][j][r] + bias[c0 + j*16 + lm];
        }
    }
  }
}

// ---------------- small GEMM (m97 structure): C[m][n] = A[m][:] . W[n][:] ----------------
// A: external (dtype per flag) with optional gather, or internal bf16 (aExt=0).
// W: always internal bf16. cmode: 0 = bf16 C, 2 = fp32 C (+bias, optional scatter).
__global__ __launch_bounds__(256) void gemm_bt(
    const void* __restrict__ A, const u16* __restrict__ W,
    void* __restrict__ C, int M,
    const int* __restrict__ gatherA, const int* __restrict__ scatterC,
    const float* __restrict__ bias, int cmode, int aExt,
    const int* __restrict__ flagp)
{
  __shared__ __align__(16) u16 As[128*32];
  __shared__ __align__(16) u16 Bs[128*32];
  const int aF32 = *flagp & aExt;
  const int tid = threadIdx.x;
  const int w = tid >> 6, l = tid & 63;
  const int mBase = blockIdx.y * 128;
  const int nBase = blockIdx.x * 128;

  const int r0 = tid >> 2;
  const int kc = (tid & 3) * 8;
  int arow0 = mBase + r0;       if (arow0 > M-1) arow0 = M-1;
  int arow1 = mBase + 64 + r0;  if (arow1 > M-1) arow1 = M-1;
  if (gatherA){ arow0 = gatherA[arow0]; arow1 = gatherA[arow1]; }
  const size_t aoff0 = (size_t)arow0 * 768 + kc;
  const size_t aoff1 = (size_t)arow1 * 768 + kc;
  const u16* bg0 = W + (size_t)(nBase + r0) * 768 + kc;
  const u16* bg1 = W + (size_t)(nBase + 64 + r0) * 768 + kc;
  u16* as0 = &As[tid * 8];
  u16* as1 = &As[(256 + tid) * 8];
  u16* bs0 = &Bs[tid * 8];
  u16* bs1 = &Bs[(256 + tid) * 8];

  f32x4 acc[4][4] = {};
  const int wm = (w >> 1) * 64, wn = (w & 1) * 64;
  const int lm = l & 15, lk = (l >> 4) * 8;
  const u16* A16 = (const u16*)A; const float* A32 = (const float*)A;

  for (int k0 = 0; k0 < 768; k0 += 32){
    async16(bg0 + k0, bs0);
    async16(bg1 + k0, bs1);
    if (aF32){
      bf16x8 v;
      f32x4 f0 = *(const f32x4*)(A32 + aoff0 + k0);
      f32x4 f1 = *(const f32x4*)(A32 + aoff0 + k0 + 4);
#pragma unroll
      for (int j = 0; j < 4; ++j){ v[j] = (short)f2b(f0[j]); v[4+j] = (short)f2b(f1[j]); }
      *(bf16x8*)as0 = v;
      f0 = *(const f32x4*)(A32 + aoff1 + k0);
      f1 = *(const f32x4*)(A32 + aoff1 + k0 + 4);
#pragma unroll
      for (int j = 0; j < 4; ++j){ v[j] = (short)f2b(f0[j]); v[4+j] = (short)f2b(f1[j]); }
      *(bf16x8*)as1 = v;
    } else {
      async16(A16 + aoff0 + k0, as0);
      async16(A16 + aoff1 + k0, as1);
    }
    __syncthreads();
    bf16x8 af[4], bfr[4];
#pragma unroll
    for (int i = 0; i < 4; ++i) af[i]  = *(const bf16x8*)&As[(wm + i*16 + lm)*32 + lk];
#pragma unroll
    for (int j = 0; j < 4; ++j) bfr[j] = *(const bf16x8*)&Bs[(wn + j*16 + lm)*32 + lk];
#pragma unroll
    for (int i = 0; i < 4; ++i)
#pragma unroll
      for (int j = 0; j < 4; ++j)
        acc[i][j] = __builtin_amdgcn_mfma_f32_16x16x32_bf16(af[i], bfr[j], acc[i][j], 0, 0, 0);
    __syncthreads();
  }

#pragma unroll
  for (int i = 0; i < 4; ++i){
#pragma unroll
    for (int r = 0; r < 4; ++r){
      int m = mBase + wm + i*16 + ((l >> 4) << 2) + r;
      if (m < M){
        int orow = scatterC ? scatterC[m] : m;
        size_t base = (size_t)orow * 768;
#pragma unroll
        for (int j = 0; j < 4; ++j){
          int n = nBase + wn + j*16 + lm;
          float v = acc[i][j][r];
          if (bias) v += bias[n];
          if (cmode == 2) ((float*)C)[base + n] = v;
          else            ((u16*)C)[base + n] = f2b(v);
        }
      }
    }
  }
}

// ---------------- attention: per (m-tile of 16, h, b); exact two-pass softmax ----------------
#define SLD 612   // score LDS row stride (608 data cols + 4 pad)
__global__ __launch_bounds__(256) void attn_kernel(
    const u16* __restrict__ lq, const u16* __restrict__ K,
    const u16* __restrict__ Vt, u16* __restrict__ lout)
{
  const int mt = blockIdx.x, h = blockIdx.y, b = blockIdx.z;
  __shared__ __align__(16) u16 qs[16*64];
  __shared__ __align__(16) float S[16*SLD];
  __shared__ float red[16*17];
  const int tid = threadIdx.x, w = tid >> 6, l = tid & 63;
  const int lm = l & 15, lk = (l >> 4) * 8;

  for (int idx = tid; idx < 1024; idx += 256){
    int r = idx >> 6, c = idx & 63;
    int gm = mt*16 + r;
    qs[idx] = (gm < 58) ? lq[((size_t)b*58 + gm)*768 + h*64 + c] : (u16)0;
  }
  __syncthreads();
  bf16x8 aq0 = *(const bf16x8*)&qs[lm*64 + lk];
  bf16x8 aq1 = *(const bf16x8*)&qs[lm*64 + 32 + lk];

  const u16* Kb = K + (size_t)b*577*768 + h*64;
  for (int t = w; t < 38; t += 4){
    int n0 = t*16;
    int n = n0 + lm; if (n > 576) n = 576;
    const u16* kp = Kb + (size_t)n*768;
    bf16x8 b0 = *(const bf16x8*)&kp[lk];
    bf16x8 b1 = *(const bf16x8*)&kp[32 + lk];
    f32x4 c = {};
    c = __builtin_amdgcn_mfma_f32_16x16x32_bf16(aq0, b0, c, 0, 0, 0);
    c = __builtin_amdgcn_mfma_f32_16x16x32_bf16(aq1, b1, c, 0, 0, 0);
#pragma unroll
    for (int r = 0; r < 4; ++r)
      S[(((l >> 4) << 2) + r)*SLD + n0 + lm] = c[r] * 0.125f;
  }
  __syncthreads();

  const int row = tid >> 4, g = tid & 15;
  float mx = -1e30f;
  for (int n = g; n < 577; n += 16) mx = fmaxf(mx, S[row*SLD + n]);
  red[row*17 + g] = mx;
  __syncthreads();
  float m2 = red[row*17];
#pragma unroll
  for (int i = 1; i < 16; ++i) m2 = fmaxf(m2, red[row*17 + i]);
  float sum = 0.f;
  for (int n = g; n < 577; n += 16){
    float e = __expf(S[row*SLD + n] - m2);
    S[row*SLD + n] = e;
    sum += e;
  }
  __syncthreads();
  red[row*17 + g] = sum;
  __syncthreads();
  float s2 = 0.f;
#pragma unroll
  for (int i = 0; i < 16; ++i) s2 += red[row*17 + i];
  float inv = 1.f / s2;
  for (int n = g; n < 577; n += 16) S[row*SLD + n] *= inv;
  for (int n = 577 + g; n < 608; n += 16) S[row*SLD + n] = 0.f;
  __syncthreads();

  const u16* Vb = Vt + ((size_t)(b*12 + h) * 64) * 608;
  f32x4 oc = {};
  for (int ks = 0; ks < 19; ++ks){
    int kb = ks*32 + lk;
    f32x4 p0 = *(const f32x4*)&S[lm*SLD + kb];
    f32x4 p1 = *(const f32x4*)&S[lm*SLD + kb + 4];
    bf16x8 af;
#pragma unroll
    for (int j = 0; j < 4; ++j){ af[j] = (short)f2b(p0[j]); af[4+j] = (short)f2b(p1[j]); }
    bf16x8 bv = *(const bf16x8*)&Vb[(size_t)(w*16 + lm)*608 + kb];
    oc = __builtin_amdgcn_mfma_f32_16x16x32_bf16(af, bv, oc, 0, 0, 0);
  }
#pragma unroll
  for (int r = 0; r < 4; ++r){
    int ml = mt*16 + ((l >> 4) << 2) + r;
    if (ml < 58)
      lout[((size_t)b*58 + ml)*768 + h*64 + w*16 + lm] = f2b(oc[r]);
  }
}

// ---------------- launch ----------------
extern "C" void kernel_launch(void* const* d_in, const int* in_sizes, int n_in,
                              void* d_out, int out_size, void* d_ws, size_t ws_size,
                              hipStream_t stream)
{
  const void* x    = d_in[0];
  const void* aacc = d_in[1];
  const void* q_w  = d_in[2];
  const void* k_w  = d_in[3];
  const void* v_w  = d_in[4];
  const void* p_w  = d_in[5];
  const void* p_b  = d_in[6];

  const int M  = 36928;   // 64*577
  const int Ms = 3712;    // 64*58
  const int WE = 768*768; // 589,824

  u16* Kbuf = (u16*)d_ws;                              // 36928*768
  u16* Vt   = Kbuf + (size_t)M * 768;                  // 768*64*608
  u16* lq   = Vt + (size_t)768 * 64 * 608;             // 3712*768
  u16* lout = lq + (size_t)Ms * 768;                   // 3712*768
  u16* kwb  = lout + (size_t)Ms * 768;                 // W3 = [k; v; p] contiguous
  u16* vwb  = kwb + WE;
  u16* pwb  = vwb + WE;
  u16* qwb  = pwb + WE;
  float* biasf = (float*)(qwb + WE);                   // 768 fp32
  int* qrows = (int*)(biasf + 768);                    // 3712 ints
  int* flagp = qrows + 3712;

  probe_kernel<<<1, 64, 0, stream>>>((const u16*)q_w, flagp);
  cvt_kernel<<<WE/8/256, 256, 0, stream>>>(k_w, kwb, WE, flagp);
  cvt_kernel<<<WE/8/256, 256, 0, stream>>>(v_w, vwb, WE, flagp);
  cvt_kernel<<<WE/8/256, 256, 0, stream>>>(p_w, pwb, WE, flagp);
  cvt_kernel<<<WE/8/256, 256, 0, stream>>>(q_w, qwb, WE, flagp);
  cvtb_kernel<<<3, 256, 0, stream>>>(p_b, biasf, 768, flagp);
  topk_kernel<<<64, 576, 0, stream>>>(aacc, qrows, flagp);

  // fused: K | Vt | proj-out  (one barrier per block, barrier-free K-loop)
  gemm_fused<<<577, 256, 0, stream>>>(x, kwb, Kbuf, Vt, (float*)d_out, biasf, flagp);
  // local_q = x[sel rows] @ q_w^T
  gemm_bt<<<dim3(6, 29), 256, 0, stream>>>(x, qwb, lq, Ms, qrows, nullptr, nullptr, 0, 1, flagp);
  // attention -> local_out
  attn_kernel<<<dim3(4, 12, 64), 256, 0, stream>>>(lq, Kbuf, Vt, lout);
  // overwrite selected rows: out[qrows] = local_out @ proj_w^T + b
  gemm_bt<<<dim3(6, 29), 256, 0, stream>>>(lout, pwb, d_out, Ms, nullptr, qrows, biasf, 2, 0, flagp);
}